// Round 6
// baseline (3634.058 us; speedup 1.0000x reference)
//
#include <hip/hip_runtime.h>

// ---------------------------------------------------------------------------
// 2-layer GCN via device-built CSR (bucketed two-level counting sort):
//   bhist -> bscan -> binA(bucketed binning) -> bucket(LDS hist+scan+scatter)
//   h1 = x @ W1                        (n x 16)
//   z1 = relu(D^-1/2 A D^-1/2 h1 + b1) CSR gather, C=16
//   pre = D^-1/2 A D^-1/2 z1           CSR gather, C=16 (aggregate-first)
//   out = pre @ W2 + b2                (n x 32)
// Bucket = 256 consecutive dst nodes. Packing (dlow<<18)|src requires
// n < 2^18 (n=200000 ok). bbuf aliases bufA/bufB (dead until k_mm1).
// ---------------------------------------------------------------------------

#define TPB 256

__device__ __forceinline__ int clampi(int v, int n) {
    return v < 0 ? 0 : (v >= n ? n - 1 : v);
}

// --- bucket histogram: bcnt[d>>8]++ --------------------------------------
__global__ void k_bhist(const int* __restrict__ dst, int E, int n,
                        int* __restrict__ bcnt) {
    int i = blockIdx.x * blockDim.x + threadIdx.x;
    int stride = gridDim.x * blockDim.x;
    for (; i < E; i += stride) atomicAdd(&bcnt[clampi(dst[i], n) >> 8], 1);
}

// --- tiny exclusive scan over buckets; btail = bstart --------------------
__global__ void k_bscan(const int* __restrict__ bcnt, int nbuck,
                        int* __restrict__ bstart, int* __restrict__ btail) {
    if (threadIdx.x == 0) {
        int run = 0;
        for (int i = 0; i < nbuck; ++i) {
            bstart[i] = run;
            run += bcnt[i];
        }
        bstart[nbuck] = run;
    }
    __syncthreads();
    for (int i = threadIdx.x; i < nbuck; i += blockDim.x) btail[i] = bstart[i];
}

// --- binning: bbuf[btail[b]++] = (dlow<<18)|s ----------------------------
__global__ void k_binA(const int* __restrict__ src, const int* __restrict__ dst,
                       int E, int n, int* __restrict__ btail,
                       int* __restrict__ bbuf) {
    int i = blockIdx.x * blockDim.x + threadIdx.x;
    int stride = gridDim.x * blockDim.x;
    for (; i < E; i += stride) {
        int s = clampi(src[i], n);
        int d = clampi(dst[i], n);
        int pos = atomicAdd(&btail[d >> 8], 1);
        bbuf[pos] = ((d & 255) << 18) | s;
    }
}

// --- per-bucket: LDS hist -> scan -> rp/dinv -> clustered scatter --------
// one block (256 thr) per bucket. rp[v] = inclusive row end in adj.
__global__ void k_bucket(const int* __restrict__ bbuf,
                         const int* __restrict__ bstart, int n,
                         int* __restrict__ rp, float* __restrict__ dinv,
                         int* __restrict__ adj) {
    __shared__ int lcnt[256];
    __shared__ int lsum[256];
    const int b = blockIdx.x;
    const int t = threadIdx.x;
    const int start = bstart[b];
    const int end = bstart[b + 1];

    lcnt[t] = 0;
    __syncthreads();
    for (int i = start + t; i < end; i += 256)
        atomicAdd(&lcnt[((unsigned)bbuf[i]) >> 18], 1);
    __syncthreads();

    int c = lcnt[t];
    lsum[t] = c;
    __syncthreads();
#pragma unroll
    for (int off = 1; off < 256; off <<= 1) {
        int v = (t >= off) ? lsum[t - off] : 0;
        __syncthreads();
        lsum[t] += v;
        __syncthreads();
    }
    // lsum[t] = inclusive prefix; exclusive = lsum[t]-c
    int v = (b << 8) + t;
    if (v < n) {
        rp[v] = start + lsum[t];
        dinv[v] = rsqrtf((float)(c + 1));
    }
    int cur0 = start + lsum[t] - c;
    __syncthreads();
    lcnt[t] = cur0;  // reuse as write cursor
    __syncthreads();

    for (int i = start + t; i < end; i += 256) {
        int p = bbuf[i];
        int dl = ((unsigned)p) >> 18;
        int s = p & 0x3FFFF;
        int pos = atomicAdd(&lcnt[dl], 1);
        adj[pos] = s;
    }
}

// --- h1 = x @ W1   (x: n x 128, W1: 128 x 16) ----------------------------
__global__ void k_mm1(const float* __restrict__ x, const float* __restrict__ W,
                      int n, float* __restrict__ h) {
    __shared__ float Ws[128 * 16];
    for (int i = threadIdx.x; i < 128 * 16; i += blockDim.x) Ws[i] = W[i];
    __syncthreads();
    int i = blockIdx.x * blockDim.x + threadIdx.x;
    int stride = gridDim.x * blockDim.x;
    for (; i < n; i += stride) {
        const float4* xr = (const float4*)(x + (size_t)i * 128);
        float acc[16];
#pragma unroll
        for (int hh = 0; hh < 16; ++hh) acc[hh] = 0.f;
#pragma unroll
        for (int j = 0; j < 32; ++j) {
            float4 v = xr[j];
            const float* w0 = &Ws[(4 * j) * 16];
#pragma unroll
            for (int hh = 0; hh < 16; ++hh)
                acc[hh] += v.x * w0[hh] + v.y * w0[16 + hh] +
                           v.z * w0[32 + hh] + v.w * w0[48 + hh];
        }
        float4* o = (float4*)(h + (size_t)i * 16);
#pragma unroll
        for (int j = 0; j < 4; ++j)
            o[j] = make_float4(acc[4 * j], acc[4 * j + 1], acc[4 * j + 2],
                               acc[4 * j + 3]);
    }
}

// --- CSR gather + finalize, C=16 -----------------------------------------
template <bool RELU, bool BIAS>
__global__ void k_gather16(const int* __restrict__ rp,
                           const int* __restrict__ adj,
                           const float* __restrict__ dinv,
                           const float* __restrict__ h,
                           const float* __restrict__ bias,
                           float* __restrict__ o, int n) {
    long long total = (long long)n * 16;
    long long i = (long long)blockIdx.x * blockDim.x + threadIdx.x;
    long long stride = (long long)gridDim.x * blockDim.x;
    for (; i < total; i += stride) {
        int v = (int)(i >> 4);
        int j = (int)(i & 15);
        int start = (v == 0) ? 0 : rp[v - 1];
        int end = rp[v];
        float acc0 = 0.f, acc1 = 0.f;
        int k = start;
        for (; k + 1 < end; k += 2) {
            int s0 = adj[k], s1 = adj[k + 1];
            acc0 += dinv[s0] * h[(size_t)s0 * 16 + j];
            acc1 += dinv[s1] * h[(size_t)s1 * 16 + j];
        }
        if (k < end) {
            int s0 = adj[k];
            acc0 += dinv[s0] * h[(size_t)s0 * 16 + j];
        }
        float dv = dinv[v];
        float val = dv * (acc0 + acc1) + dv * dv * h[i];
        if (BIAS) val += bias[j];
        if (RELU) val = fmaxf(val, 0.f);
        o[i] = val;
    }
}

// --- out = pre @ W2 + b2   (pre: n x 16, W2: 16 x 32) --------------------
__global__ void k_out(const float* __restrict__ pre,
                      const float* __restrict__ W2,
                      const float* __restrict__ b2, float* __restrict__ out,
                      int n) {
    __shared__ float Ws[16 * 32];
    for (int i = threadIdx.x; i < 16 * 32; i += blockDim.x) Ws[i] = W2[i];
    __syncthreads();
    long long total = (long long)n * 32;
    long long i = (long long)blockIdx.x * blockDim.x + threadIdx.x;
    long long stride = (long long)gridDim.x * blockDim.x;
    for (; i < total; i += stride) {
        int v = (int)(i >> 5);
        int c = (int)(i & 31);
        const float* pr = pre + (size_t)v * 16;
        float acc = b2[c];
#pragma unroll
        for (int j = 0; j < 16; ++j) acc += pr[j] * Ws[j * 32 + c];
        out[i] = acc;
    }
}

static inline int capped_blocks(long long total, int cap) {
    long long b = (total + TPB - 1) / TPB;
    return (int)(b < cap ? b : cap);
}

extern "C" void kernel_launch(void* const* d_in, const int* in_sizes, int n_in,
                              void* d_out, int out_size, void* d_ws,
                              size_t ws_size, hipStream_t stream) {
    const float* x = (const float*)d_in[0];
    const int* ei = (const int*)d_in[1];
    const float* W1 = (const float*)d_in[2];
    const float* b1 = (const float*)d_in[3];
    const float* W2 = (const float*)d_in[4];
    const float* b2 = (const float*)d_in[5];
    float* out = (float*)d_out;

    const int n = in_sizes[0] / 128;  // 200000 nodes
    const int E = in_sizes[1] / 2;    // 6400000 edges
    const int* src = ei;
    const int* dst = ei + E;
    const int nbuck = (n + 255) / 256;  // 782

    // workspace layout:
    //  dinv: n f32 | rp: n i32 | adj: E i32 | bufA: n*16 f32 | bufB: n*16 f32
    //  bmeta (bcnt, bstart, btail) after bufB. bbuf aliases bufA+bufB.
    char* ws = (char*)d_ws;
    float* dinv = (float*)ws;
    int* rp = (int*)(ws + (size_t)n * 4);
    int* adj = (int*)(ws + (size_t)n * 8);
    float* bufA = (float*)(ws + (size_t)n * 8 + (size_t)E * 4);
    float* bufB = bufA + (size_t)n * 16;
    int* bcnt = (int*)(bufB + (size_t)n * 16);
    int* bstart = bcnt + nbuck;
    int* btail = bstart + nbuck + 1;
    int* bbuf = (int*)bufA;  // E ints, dead once k_mm1 runs

    // --- CSR build ---
    hipMemsetAsync(bcnt, 0, (size_t)nbuck * 4, stream);
    k_bhist<<<capped_blocks(E, 8192), TPB, 0, stream>>>(dst, E, n, bcnt);
    k_bscan<<<1, 256, 0, stream>>>(bcnt, nbuck, bstart, btail);
    k_binA<<<capped_blocks(E, 8192), TPB, 0, stream>>>(src, dst, E, n, btail,
                                                       bbuf);
    k_bucket<<<nbuck, 256, 0, stream>>>(bbuf, bstart, n, rp, dinv, adj);

    // --- layer 1: h1 = x@W1 ; z1 = relu(agg(h1) + b1) ---
    k_mm1<<<(n + TPB - 1) / TPB, TPB, 0, stream>>>(x, W1, n, bufA);
    k_gather16<true, true><<<capped_blocks((long long)n * 16, 8192), TPB, 0,
                             stream>>>(rp, adj, dinv, bufA, b1, bufB, n);

    // --- layer 2: pre = agg(z1) ; out = pre@W2 + b2 ---
    k_gather16<false, false><<<capped_blocks((long long)n * 16, 8192), TPB, 0,
                               stream>>>(rp, adj, dinv, bufB, nullptr, bufA, n);
    k_out<<<capped_blocks((long long)n * 32, 8192), TPB, 0, stream>>>(
        bufA, W2, b2, out, n);
}

// Round 7
// 770.786 us; speedup vs baseline: 4.7147x; 4.7147x over previous
//
#include <hip/hip_runtime.h>

// ---------------------------------------------------------------------------
// 2-layer GCN via device-built CSR. CSR build = deterministic two-level
// counting sort with per-block histograms (NO global atomics anywhere):
//   k_hist  : per-block LDS hist of its edge range -> hist[b][k] (coalesced)
//   k_scanA : column scan over blocks -> in-place per-block offsets + colsum
//   k_scanB : exclusive scan of colsum -> bstart (bucket bases)
//   k_bin   : cursors = bstart[k]+hist[b][k] in LDS; scatter packed
//             (dlow<<18)|src into bbuf; per-block runs are contiguous
//   k_bucket: per-bucket LDS hist+scan -> rp/dinv, clustered scatter -> adj
// Then: h1 = x@W1 ; z1 = relu(agg(h1)+b1) ; pre = agg(z1) ; out = pre@W2+b2
// (aggregate-first on layer 2: aggregation is linear).
// Bucket = 256 consecutive dst nodes; packing needs n < 2^18 (n=200000 ok,
// nbuck = 782 <= 1024). bbuf aliases bufA+bufB (dead until k_mm1).
// ---------------------------------------------------------------------------

#define TPB 256
#define NB 128          // bin blocks (per-block hist rows)
#define BINT 1024       // threads per bin/hist block

__device__ __forceinline__ int clampi(int v, int n) {
    return v < 0 ? 0 : (v >= n ? n - 1 : v);
}

// --- per-block LDS histogram over contiguous range; no global atomics ----
__global__ __launch_bounds__(BINT) void k_hist(const int* __restrict__ dst,
                                               int E, int n, int nbuck,
                                               int chunk,
                                               int* __restrict__ hist) {
    __shared__ int lh[1024];
    const int b = blockIdx.x;
    const int t = threadIdx.x;
    for (int k = t; k < 1024; k += BINT) lh[k] = 0;
    __syncthreads();
    const int start = b * chunk;
    const int end = min(E, start + chunk);
    for (int i = start + t; i < end; i += BINT)
        atomicAdd(&lh[clampi(dst[i], n) >> 8], 1);
    __syncthreads();
    for (int k = t; k < nbuck; k += BINT) hist[b * nbuck + k] = lh[k];
}

// --- column scan: hist[b][k] -> exclusive prefix over b; colsum[k] -------
__global__ void k_scanA(int* __restrict__ hist, int nbuck,
                        int* __restrict__ colsum) {
    int k = blockIdx.x * blockDim.x + threadIdx.x;
    if (k >= nbuck) return;
    int run = 0;
    for (int b = 0; b < NB; ++b) {
        int v = hist[b * nbuck + k];
        hist[b * nbuck + k] = run;
        run += v;
    }
    colsum[k] = run;
}

// --- exclusive scan of colsum -> bstart[0..nbuck] ------------------------
__global__ void k_scanB(const int* __restrict__ colsum, int nbuck, int E,
                        int* __restrict__ bstart) {
    __shared__ int s[256];
    const int t = threadIdx.x;
    int loc[4];
    int a = 0;
#pragma unroll
    for (int i = 0; i < 4; ++i) {
        int idx = 4 * t + i;
        loc[i] = (idx < nbuck) ? colsum[idx] : 0;
        a += loc[i];
    }
    s[t] = a;
    __syncthreads();
#pragma unroll
    for (int off = 1; off < 256; off <<= 1) {
        int v = (t >= off) ? s[t - off] : 0;
        __syncthreads();
        s[t] += v;
        __syncthreads();
    }
    int base = s[t] - a;  // exclusive prefix of this thread's 4-group
#pragma unroll
    for (int i = 0; i < 4; ++i) {
        int idx = 4 * t + i;
        if (idx < nbuck) bstart[idx] = base;
        base += loc[i];
    }
    if (t == 255) bstart[nbuck] = E;
}

// --- binning: LDS cursors (bstart+per-block offset), LDS atomics only ----
__global__ __launch_bounds__(BINT) void k_bin(const int* __restrict__ src,
                                              const int* __restrict__ dst,
                                              int E, int n, int nbuck,
                                              int chunk,
                                              const int* __restrict__ hist,
                                              const int* __restrict__ bstart,
                                              int* __restrict__ bbuf) {
    __shared__ int lcur[1024];
    const int b = blockIdx.x;
    const int t = threadIdx.x;
    for (int k = t; k < nbuck; k += BINT)
        lcur[k] = bstart[k] + hist[b * nbuck + k];
    __syncthreads();
    const int start = b * chunk;
    const int end = min(E, start + chunk);
    for (int i = start + t; i < end; i += BINT) {
        int s = clampi(src[i], n);
        int d = clampi(dst[i], n);
        int pos = atomicAdd(&lcur[d >> 8], 1);
        bbuf[pos] = ((d & 255) << 18) | s;
    }
}

// --- per-bucket: LDS hist -> scan -> rp/dinv -> clustered scatter --------
__global__ void k_bucket(const int* __restrict__ bbuf,
                         const int* __restrict__ bstart, int n,
                         int* __restrict__ rp, float* __restrict__ dinv,
                         int* __restrict__ adj) {
    __shared__ int lcnt[256];
    __shared__ int lsum[256];
    const int b = blockIdx.x;
    const int t = threadIdx.x;
    const int start = bstart[b];
    const int end = bstart[b + 1];

    lcnt[t] = 0;
    __syncthreads();
    for (int i = start + t; i < end; i += 256)
        atomicAdd(&lcnt[((unsigned)bbuf[i]) >> 18], 1);
    __syncthreads();

    int c = lcnt[t];
    lsum[t] = c;
    __syncthreads();
#pragma unroll
    for (int off = 1; off < 256; off <<= 1) {
        int v = (t >= off) ? lsum[t - off] : 0;
        __syncthreads();
        lsum[t] += v;
        __syncthreads();
    }
    int v = (b << 8) + t;
    if (v < n) {
        rp[v] = start + lsum[t];  // inclusive row end
        dinv[v] = rsqrtf((float)(c + 1));
    }
    int cur0 = start + lsum[t] - c;
    __syncthreads();
    lcnt[t] = cur0;  // reuse as write cursor
    __syncthreads();

    for (int i = start + t; i < end; i += 256) {
        int p = bbuf[i];
        int dl = ((unsigned)p) >> 18;
        int s = p & 0x3FFFF;
        int pos = atomicAdd(&lcnt[dl], 1);
        adj[pos] = s;
    }
}

// --- h1 = x @ W1   (x: n x 128, W1: 128 x 16) ----------------------------
__global__ void k_mm1(const float* __restrict__ x, const float* __restrict__ W,
                      int n, float* __restrict__ h) {
    __shared__ float Ws[128 * 16];
    for (int i = threadIdx.x; i < 128 * 16; i += blockDim.x) Ws[i] = W[i];
    __syncthreads();
    int i = blockIdx.x * blockDim.x + threadIdx.x;
    int stride = gridDim.x * blockDim.x;
    for (; i < n; i += stride) {
        const float4* xr = (const float4*)(x + (size_t)i * 128);
        float acc[16];
#pragma unroll
        for (int hh = 0; hh < 16; ++hh) acc[hh] = 0.f;
#pragma unroll
        for (int j = 0; j < 32; ++j) {
            float4 v = xr[j];
            const float* w0 = &Ws[(4 * j) * 16];
#pragma unroll
            for (int hh = 0; hh < 16; ++hh)
                acc[hh] += v.x * w0[hh] + v.y * w0[16 + hh] +
                           v.z * w0[32 + hh] + v.w * w0[48 + hh];
        }
        float4* o = (float4*)(h + (size_t)i * 16);
#pragma unroll
        for (int j = 0; j < 4; ++j)
            o[j] = make_float4(acc[4 * j], acc[4 * j + 1], acc[4 * j + 2],
                               acc[4 * j + 3]);
    }
}

// --- CSR gather + finalize, C=16 -----------------------------------------
template <bool RELU, bool BIAS>
__global__ void k_gather16(const int* __restrict__ rp,
                           const int* __restrict__ adj,
                           const float* __restrict__ dinv,
                           const float* __restrict__ h,
                           const float* __restrict__ bias,
                           float* __restrict__ o, int n) {
    long long total = (long long)n * 16;
    long long i = (long long)blockIdx.x * blockDim.x + threadIdx.x;
    long long stride = (long long)gridDim.x * blockDim.x;
    for (; i < total; i += stride) {
        int v = (int)(i >> 4);
        int j = (int)(i & 15);
        int start = (v == 0) ? 0 : rp[v - 1];
        int end = rp[v];
        float acc0 = 0.f, acc1 = 0.f;
        int k = start;
        for (; k + 1 < end; k += 2) {
            int s0 = adj[k], s1 = adj[k + 1];
            acc0 += dinv[s0] * h[(size_t)s0 * 16 + j];
            acc1 += dinv[s1] * h[(size_t)s1 * 16 + j];
        }
        if (k < end) {
            int s0 = adj[k];
            acc0 += dinv[s0] * h[(size_t)s0 * 16 + j];
        }
        float dv = dinv[v];
        float val = dv * (acc0 + acc1) + dv * dv * h[i];
        if (BIAS) val += bias[j];
        if (RELU) val = fmaxf(val, 0.f);
        o[i] = val;
    }
}

// --- out = pre @ W2 + b2   (pre: n x 16, W2: 16 x 32) --------------------
__global__ void k_out(const float* __restrict__ pre,
                      const float* __restrict__ W2,
                      const float* __restrict__ b2, float* __restrict__ out,
                      int n) {
    __shared__ float Ws[16 * 32];
    for (int i = threadIdx.x; i < 16 * 32; i += blockDim.x) Ws[i] = W2[i];
    __syncthreads();
    long long total = (long long)n * 32;
    long long i = (long long)blockIdx.x * blockDim.x + threadIdx.x;
    long long stride = (long long)gridDim.x * blockDim.x;
    for (; i < total; i += stride) {
        int v = (int)(i >> 5);
        int c = (int)(i & 31);
        const float* pr = pre + (size_t)v * 16;
        float acc = b2[c];
#pragma unroll
        for (int j = 0; j < 16; ++j) acc += pr[j] * Ws[j * 32 + c];
        out[i] = acc;
    }
}

static inline int capped_blocks(long long total, int cap) {
    long long b = (total + TPB - 1) / TPB;
    return (int)(b < cap ? b : cap);
}

extern "C" void kernel_launch(void* const* d_in, const int* in_sizes, int n_in,
                              void* d_out, int out_size, void* d_ws,
                              size_t ws_size, hipStream_t stream) {
    const float* x = (const float*)d_in[0];
    const int* ei = (const int*)d_in[1];
    const float* W1 = (const float*)d_in[2];
    const float* b1 = (const float*)d_in[3];
    const float* W2 = (const float*)d_in[4];
    const float* b2 = (const float*)d_in[5];
    float* out = (float*)d_out;

    const int n = in_sizes[0] / 128;  // 200000 nodes
    const int E = in_sizes[1] / 2;    // 6400000 edges
    const int* src = ei;
    const int* dst = ei + E;
    const int nbuck = (n + 255) / 256;        // 782 (<= 1024 required)
    const int chunk = (E + NB - 1) / NB;      // 50000 edges per bin block

    // workspace layout:
    //  dinv: n f32 | rp: n i32 | adj: E i32 | bufA: n*16 f32 | bufB: n*16 f32
    //  hist: NB*nbuck i32 | colsum: nbuck i32 | bstart: nbuck+1 i32
    //  bbuf (E i32) aliases bufA+bufB (n*32 f32 == E elements).
    char* ws = (char*)d_ws;
    float* dinv = (float*)ws;
    int* rp = (int*)(ws + (size_t)n * 4);
    int* adj = (int*)(ws + (size_t)n * 8);
    float* bufA = (float*)(ws + (size_t)n * 8 + (size_t)E * 4);
    float* bufB = bufA + (size_t)n * 16;
    int* hist = (int*)(bufB + (size_t)n * 16);
    int* colsum = hist + (size_t)NB * nbuck;
    int* bstart = colsum + nbuck;
    int* bbuf = (int*)bufA;  // E ints, dead once k_mm1 runs

    // --- CSR build (no global atomics) ---
    k_hist<<<NB, BINT, 0, stream>>>(dst, E, n, nbuck, chunk, hist);
    k_scanA<<<(nbuck + 255) / 256, 256, 0, stream>>>(hist, nbuck, colsum);
    k_scanB<<<1, 256, 0, stream>>>(colsum, nbuck, E, bstart);
    k_bin<<<NB, BINT, 0, stream>>>(src, dst, E, n, nbuck, chunk, hist, bstart,
                                   bbuf);
    k_bucket<<<nbuck, 256, 0, stream>>>(bbuf, bstart, n, rp, dinv, adj);

    // --- layer 1: h1 = x@W1 ; z1 = relu(agg(h1) + b1) ---
    k_mm1<<<(n + TPB - 1) / TPB, TPB, 0, stream>>>(x, W1, n, bufA);
    k_gather16<true, true><<<capped_blocks((long long)n * 16, 8192), TPB, 0,
                             stream>>>(rp, adj, dinv, bufA, b1, bufB, n);

    // --- layer 2: pre = agg(z1) ; out = pre@W2 + b2 ---
    k_gather16<false, false><<<capped_blocks((long long)n * 16, 8192), TPB, 0,
                               stream>>>(rp, adj, dinv, bufB, nullptr, bufA, n);
    k_out<<<capped_blocks((long long)n * 32, 8192), TPB, 0, stream>>>(
        bufA, W2, b2, out, n);
}

// Round 8
// 481.728 us; speedup vs baseline: 7.5438x; 1.6000x over previous
//
#include <hip/hip_runtime.h>

// ---------------------------------------------------------------------------
// 2-layer GCN via device-built CSR. CSR build = deterministic two-level
// counting sort with per-block histograms (NO global atomics anywhere):
//   k_hist  : per-block LDS hist of its edge range -> hist[b][k] (coalesced)
//   k_scanA : column scan over blocks -> in-place per-block offsets + colsum
//   k_scanB : exclusive scan of colsum -> bstart (bucket bases)
//   k_bin   : cursors = bstart[k]+hist[b][k] in LDS; scatter packed
//             (dlow<<18)|src into bbuf; per-block runs are contiguous
//   k_bucket: per-bucket LDS hist+scan -> rp/dinv, clustered scatter -> adj
// Then: h1 = x@W1 ; z1 = relu(agg(h1)+b1) ; pre = agg(z1) ; out = pre@W2+b2
// (aggregate-first on layer 2: aggregation is linear).
// k_mm1 is thread-per-(node,channel): 16 lanes broadcast-read the same x
// float4 (4-line live footprint per wave, zero amplification) and stores are
// lane-consecutive. The old thread-per-row layout touched 64 lines per
// instruction -> 3.2x read / 37x write amplification (round-7 counters).
// Bucket = 256 consecutive dst nodes; packing needs n < 2^18 (n=200000 ok,
// nbuck = 782 <= 1024). bbuf aliases bufA+bufB (dead until k_mm1).
// ---------------------------------------------------------------------------

#define TPB 256
#define NB 128          // bin blocks (per-block hist rows)
#define BINT 1024       // threads per bin/hist block

__device__ __forceinline__ int clampi(int v, int n) {
    return v < 0 ? 0 : (v >= n ? n - 1 : v);
}

// --- per-block LDS histogram over contiguous range; no global atomics ----
__global__ __launch_bounds__(BINT) void k_hist(const int* __restrict__ dst,
                                               int E, int n, int nbuck,
                                               int chunk,
                                               int* __restrict__ hist) {
    __shared__ int lh[1024];
    const int b = blockIdx.x;
    const int t = threadIdx.x;
    for (int k = t; k < 1024; k += BINT) lh[k] = 0;
    __syncthreads();
    const int start = b * chunk;
    const int end = min(E, start + chunk);
    for (int i = start + t; i < end; i += BINT)
        atomicAdd(&lh[clampi(dst[i], n) >> 8], 1);
    __syncthreads();
    for (int k = t; k < nbuck; k += BINT) hist[b * nbuck + k] = lh[k];
}

// --- column scan: hist[b][k] -> exclusive prefix over b; colsum[k] -------
__global__ void k_scanA(int* __restrict__ hist, int nbuck,
                        int* __restrict__ colsum) {
    int k = blockIdx.x * blockDim.x + threadIdx.x;
    if (k >= nbuck) return;
    int run = 0;
    for (int b = 0; b < NB; ++b) {
        int v = hist[b * nbuck + k];
        hist[b * nbuck + k] = run;
        run += v;
    }
    colsum[k] = run;
}

// --- exclusive scan of colsum -> bstart[0..nbuck] ------------------------
__global__ void k_scanB(const int* __restrict__ colsum, int nbuck, int E,
                        int* __restrict__ bstart) {
    __shared__ int s[256];
    const int t = threadIdx.x;
    int loc[4];
    int a = 0;
#pragma unroll
    for (int i = 0; i < 4; ++i) {
        int idx = 4 * t + i;
        loc[i] = (idx < nbuck) ? colsum[idx] : 0;
        a += loc[i];
    }
    s[t] = a;
    __syncthreads();
#pragma unroll
    for (int off = 1; off < 256; off <<= 1) {
        int v = (t >= off) ? s[t - off] : 0;
        __syncthreads();
        s[t] += v;
        __syncthreads();
    }
    int base = s[t] - a;  // exclusive prefix of this thread's 4-group
#pragma unroll
    for (int i = 0; i < 4; ++i) {
        int idx = 4 * t + i;
        if (idx < nbuck) bstart[idx] = base;
        base += loc[i];
    }
    if (t == 255) bstart[nbuck] = E;
}

// --- binning: LDS cursors (bstart+per-block offset), LDS atomics only ----
__global__ __launch_bounds__(BINT) void k_bin(const int* __restrict__ src,
                                              const int* __restrict__ dst,
                                              int E, int n, int nbuck,
                                              int chunk,
                                              const int* __restrict__ hist,
                                              const int* __restrict__ bstart,
                                              int* __restrict__ bbuf) {
    __shared__ int lcur[1024];
    const int b = blockIdx.x;
    const int t = threadIdx.x;
    for (int k = t; k < nbuck; k += BINT)
        lcur[k] = bstart[k] + hist[b * nbuck + k];
    __syncthreads();
    const int start = b * chunk;
    const int end = min(E, start + chunk);
    for (int i = start + t; i < end; i += BINT) {
        int s = clampi(src[i], n);
        int d = clampi(dst[i], n);
        int pos = atomicAdd(&lcur[d >> 8], 1);
        bbuf[pos] = ((d & 255) << 18) | s;
    }
}

// --- per-bucket: LDS hist -> scan -> rp/dinv -> clustered scatter --------
__global__ void k_bucket(const int* __restrict__ bbuf,
                         const int* __restrict__ bstart, int n,
                         int* __restrict__ rp, float* __restrict__ dinv,
                         int* __restrict__ adj) {
    __shared__ int lcnt[256];
    __shared__ int lsum[256];
    const int b = blockIdx.x;
    const int t = threadIdx.x;
    const int start = bstart[b];
    const int end = bstart[b + 1];

    lcnt[t] = 0;
    __syncthreads();
    for (int i = start + t; i < end; i += 256)
        atomicAdd(&lcnt[((unsigned)bbuf[i]) >> 18], 1);
    __syncthreads();

    int c = lcnt[t];
    lsum[t] = c;
    __syncthreads();
#pragma unroll
    for (int off = 1; off < 256; off <<= 1) {
        int v = (t >= off) ? lsum[t - off] : 0;
        __syncthreads();
        lsum[t] += v;
        __syncthreads();
    }
    int v = (b << 8) + t;
    if (v < n) {
        rp[v] = start + lsum[t];  // inclusive row end
        dinv[v] = rsqrtf((float)(c + 1));
    }
    int cur0 = start + lsum[t] - c;
    __syncthreads();
    lcnt[t] = cur0;  // reuse as write cursor
    __syncthreads();

    for (int i = start + t; i < end; i += 256) {
        int p = bbuf[i];
        int dl = ((unsigned)p) >> 18;
        int s = p & 0x3FFFF;
        int pos = atomicAdd(&lcnt[dl], 1);
        adj[pos] = s;
    }
}

// --- h1 = x @ W1, thread-per-(node,channel) ------------------------------
// i = v*16 + c. 16 lanes of a node broadcast-read the same x float4 (only
// 4 rows live per wave -> 4-line footprint); h store lane-consecutive.
__global__ void k_mm1(const float* __restrict__ x, const float* __restrict__ W,
                      int n, float* __restrict__ h) {
    __shared__ float Ws[128 * 16];
    for (int i = threadIdx.x; i < 128 * 16; i += blockDim.x) Ws[i] = W[i];
    __syncthreads();
    long long total = (long long)n * 16;
    long long i = (long long)blockIdx.x * blockDim.x + threadIdx.x;
    long long stride = (long long)gridDim.x * blockDim.x;
    for (; i < total; i += stride) {
        int v = (int)(i >> 4);
        int c = (int)(i & 15);
        const float4* xr = (const float4*)(x + (size_t)v * 128);
        float acc = 0.f;
#pragma unroll
        for (int q = 0; q < 32; ++q) {
            float4 xv = xr[q];
            acc += xv.x * Ws[(4 * q + 0) * 16 + c] +
                   xv.y * Ws[(4 * q + 1) * 16 + c] +
                   xv.z * Ws[(4 * q + 2) * 16 + c] +
                   xv.w * Ws[(4 * q + 3) * 16 + c];
        }
        h[i] = acc;
    }
}

// --- CSR gather + finalize, C=16 -----------------------------------------
template <bool RELU, bool BIAS>
__global__ void k_gather16(const int* __restrict__ rp,
                           const int* __restrict__ adj,
                           const float* __restrict__ dinv,
                           const float* __restrict__ h,
                           const float* __restrict__ bias,
                           float* __restrict__ o, int n) {
    long long total = (long long)n * 16;
    long long i = (long long)blockIdx.x * blockDim.x + threadIdx.x;
    long long stride = (long long)gridDim.x * blockDim.x;
    for (; i < total; i += stride) {
        int v = (int)(i >> 4);
        int j = (int)(i & 15);
        int start = (v == 0) ? 0 : rp[v - 1];
        int end = rp[v];
        float acc0 = 0.f, acc1 = 0.f;
        int k = start;
        for (; k + 1 < end; k += 2) {
            int s0 = adj[k], s1 = adj[k + 1];
            acc0 += dinv[s0] * h[(size_t)s0 * 16 + j];
            acc1 += dinv[s1] * h[(size_t)s1 * 16 + j];
        }
        if (k < end) {
            int s0 = adj[k];
            acc0 += dinv[s0] * h[(size_t)s0 * 16 + j];
        }
        float dv = dinv[v];
        float val = dv * (acc0 + acc1) + dv * dv * h[i];
        if (BIAS) val += bias[j];
        if (RELU) val = fmaxf(val, 0.f);
        o[i] = val;
    }
}

// --- out = pre @ W2 + b2   (pre: n x 16, W2: 16 x 32) --------------------
__global__ void k_out(const float* __restrict__ pre,
                      const float* __restrict__ W2,
                      const float* __restrict__ b2, float* __restrict__ out,
                      int n) {
    __shared__ float Ws[16 * 32];
    for (int i = threadIdx.x; i < 16 * 32; i += blockDim.x) Ws[i] = W2[i];
    __syncthreads();
    long long total = (long long)n * 32;
    long long i = (long long)blockIdx.x * blockDim.x + threadIdx.x;
    long long stride = (long long)gridDim.x * blockDim.x;
    for (; i < total; i += stride) {
        int v = (int)(i >> 5);
        int c = (int)(i & 31);
        const float* pr = pre + (size_t)v * 16;
        float acc = b2[c];
#pragma unroll
        for (int j = 0; j < 16; ++j) acc += pr[j] * Ws[j * 32 + c];
        out[i] = acc;
    }
}

static inline int capped_blocks(long long total, int cap) {
    long long b = (total + TPB - 1) / TPB;
    return (int)(b < cap ? b : cap);
}

extern "C" void kernel_launch(void* const* d_in, const int* in_sizes, int n_in,
                              void* d_out, int out_size, void* d_ws,
                              size_t ws_size, hipStream_t stream) {
    const float* x = (const float*)d_in[0];
    const int* ei = (const int*)d_in[1];
    const float* W1 = (const float*)d_in[2];
    const float* b1 = (const float*)d_in[3];
    const float* W2 = (const float*)d_in[4];
    const float* b2 = (const float*)d_in[5];
    float* out = (float*)d_out;

    const int n = in_sizes[0] / 128;  // 200000 nodes
    const int E = in_sizes[1] / 2;    // 6400000 edges
    const int* src = ei;
    const int* dst = ei + E;
    const int nbuck = (n + 255) / 256;        // 782 (<= 1024 required)
    const int chunk = (E + NB - 1) / NB;      // 50000 edges per bin block

    // workspace layout:
    //  dinv: n f32 | rp: n i32 | adj: E i32 | bufA: n*16 f32 | bufB: n*16 f32
    //  hist: NB*nbuck i32 | colsum: nbuck i32 | bstart: nbuck+1 i32
    //  bbuf (E i32) aliases bufA+bufB (n*32 f32 == E elements).
    char* ws = (char*)d_ws;
    float* dinv = (float*)ws;
    int* rp = (int*)(ws + (size_t)n * 4);
    int* adj = (int*)(ws + (size_t)n * 8);
    float* bufA = (float*)(ws + (size_t)n * 8 + (size_t)E * 4);
    float* bufB = bufA + (size_t)n * 16;
    int* hist = (int*)(bufB + (size_t)n * 16);
    int* colsum = hist + (size_t)NB * nbuck;
    int* bstart = colsum + nbuck;
    int* bbuf = (int*)bufA;  // E ints, dead once k_mm1 runs

    // --- CSR build (no global atomics) ---
    k_hist<<<NB, BINT, 0, stream>>>(dst, E, n, nbuck, chunk, hist);
    k_scanA<<<(nbuck + 255) / 256, 256, 0, stream>>>(hist, nbuck, colsum);
    k_scanB<<<1, 256, 0, stream>>>(colsum, nbuck, E, bstart);
    k_bin<<<NB, BINT, 0, stream>>>(src, dst, E, n, nbuck, chunk, hist, bstart,
                                   bbuf);
    k_bucket<<<nbuck, 256, 0, stream>>>(bbuf, bstart, n, rp, dinv, adj);

    // --- layer 1: h1 = x@W1 ; z1 = relu(agg(h1) + b1) ---
    k_mm1<<<capped_blocks((long long)n * 16, 12500), TPB, 0, stream>>>(
        x, W1, n, bufA);
    k_gather16<true, true><<<capped_blocks((long long)n * 16, 8192), TPB, 0,
                             stream>>>(rp, adj, dinv, bufA, b1, bufB, n);

    // --- layer 2: pre = agg(z1) ; out = pre@W2 + b2 ---
    k_gather16<false, false><<<capped_blocks((long long)n * 16, 8192), TPB, 0,
                               stream>>>(rp, adj, dinv, bufB, nullptr, bufA, n);
    k_out<<<capped_blocks((long long)n * 32, 8192), TPB, 0, stream>>>(
        bufA, W2, b2, out, n);
}